// Round 1
// baseline (86.760 us; speedup 1.0000x reference)
//
#include <hip/hip_runtime.h>

// out[n,m] = exp(i1[n]·i2[m] - ||i1[n]||^2/2 - ||i2[m]||^2/2)
// N=M=4096, D=32, f32. HBM-write-bound (64 MB out); tile 128x128/block.

#define D 32
#define BT 128          // block tile (rows and cols)
#define LDT 132         // LDS stride (pad: 132%32=4 rotates banks; %4==0 keeps float4 align)

__global__ __launch_bounds__(256, 4) void rbf_tile_kernel(
    const float* __restrict__ A,   // [N][32]
    const float* __restrict__ B,   // [M][32]
    float* __restrict__ out,       // [N][M]
    int M)
{
    __shared__ float sA[D][LDT];   // transposed: sA[d][row]
    __shared__ float sB[D][LDT];
    __shared__ float hnA[BT];      // 0.5*||row||^2
    __shared__ float hnB[BT];

    const int tid  = threadIdx.x;
    const int brow = blockIdx.y * BT;
    const int bcol = blockIdx.x * BT;

    // ---- stage 128x32 of each input, transposed into LDS ----
    // 1024 float4 per side; 4 per thread per side; global reads fully coalesced.
    const float4* gA = reinterpret_cast<const float4*>(A + brow * D);
    const float4* gB = reinterpret_cast<const float4*>(B + bcol * D);
    #pragma unroll
    for (int k = 0; k < 4; ++k) {
        const int i   = tid + k * 256;   // 0..1023
        const int row = i >> 3;          // 0..127
        const int d0  = (i & 7) << 2;    // 0,4,...,28
        float4 va = gA[i];
        float4 vb = gB[i];
        sA[d0 + 0][row] = va.x; sA[d0 + 1][row] = va.y;
        sA[d0 + 2][row] = va.z; sA[d0 + 3][row] = va.w;
        sB[d0 + 0][row] = vb.x; sB[d0 + 1][row] = vb.y;
        sB[d0 + 2][row] = vb.z; sB[d0 + 3][row] = vb.w;
    }
    __syncthreads();

    // ---- half-norms ----
    if (tid < BT) {
        float s = 0.f;
        #pragma unroll
        for (int d = 0; d < D; ++d) { float v = sA[d][tid]; s += v * v; }
        hnA[tid] = 0.5f * s;
    } else {
        const int r = tid - BT;
        float s = 0.f;
        #pragma unroll
        for (int d = 0; d < D; ++d) { float v = sB[d][r]; s += v * v; }
        hnB[r] = 0.5f * s;
    }
    __syncthreads();

    // ---- 8x8 register tile per thread ----
    const int g   = tid >> 4;        // 0..15 row group
    const int c   = tid & 15;        // 0..15 col group
    const int tr  = g * 8;           // rows tr..tr+7
    const int tc0 = c * 4;           // cols tc0..tc0+3
    const int tc1 = c * 4 + 64;      // cols tc1..tc1+3

    float acc[8][8];
    #pragma unroll
    for (int i = 0; i < 8; ++i)
        #pragma unroll
        for (int j = 0; j < 8; ++j) acc[i][j] = 0.f;

    #pragma unroll
    for (int d = 0; d < D; ++d) {
        const float4 a0 = *reinterpret_cast<const float4*>(&sA[d][tr]);
        const float4 a1 = *reinterpret_cast<const float4*>(&sA[d][tr + 4]);
        const float4 b0 = *reinterpret_cast<const float4*>(&sB[d][tc0]);
        const float4 b1 = *reinterpret_cast<const float4*>(&sB[d][tc1]);
        const float av[8] = {a0.x, a0.y, a0.z, a0.w, a1.x, a1.y, a1.z, a1.w};
        const float bv[8] = {b0.x, b0.y, b0.z, b0.w, b1.x, b1.y, b1.z, b1.w};
        #pragma unroll
        for (int i = 0; i < 8; ++i)
            #pragma unroll
            for (int j = 0; j < 8; ++j)
                acc[i][j] += av[i] * bv[j];
    }

    // ---- epilogue: exp + coalesced float4 stores ----
    float hna[8], hnb[8];
    #pragma unroll
    for (int i = 0; i < 8; ++i) hna[i] = hnA[tr + i];
    #pragma unroll
    for (int j = 0; j < 4; ++j) { hnb[j] = hnB[tc0 + j]; hnb[j + 4] = hnB[tc1 + j]; }

    #pragma unroll
    for (int i = 0; i < 8; ++i) {
        const float h = hna[i];
        float4 o0, o1;
        o0.x = __expf(acc[i][0] - h - hnb[0]);
        o0.y = __expf(acc[i][1] - h - hnb[1]);
        o0.z = __expf(acc[i][2] - h - hnb[2]);
        o0.w = __expf(acc[i][3] - h - hnb[3]);
        o1.x = __expf(acc[i][4] - h - hnb[4]);
        o1.y = __expf(acc[i][5] - h - hnb[5]);
        o1.z = __expf(acc[i][6] - h - hnb[6]);
        o1.w = __expf(acc[i][7] - h - hnb[7]);
        float* r = out + (size_t)(brow + tr + i) * M + bcol;
        *reinterpret_cast<float4*>(r + tc0) = o0;
        *reinterpret_cast<float4*>(r + tc1) = o1;
    }
}

extern "C" void kernel_launch(void* const* d_in, const int* in_sizes, int n_in,
                              void* d_out, int out_size, void* d_ws, size_t ws_size,
                              hipStream_t stream) {
    const float* A = (const float*)d_in[0];
    const float* B = (const float*)d_in[1];
    float* out     = (float*)d_out;
    const int N = in_sizes[0] / D;   // 4096
    const int M = in_sizes[1] / D;   // 4096
    dim3 grid(M / BT, N / BT);       // 32 x 32
    rbf_tile_kernel<<<grid, 256, 0, stream>>>(A, B, out, M);
}